// Round 8
// baseline (576.907 us; speedup 1.0000x reference)
//
#include <hip/hip_runtime.h>

#define N_NODES 50000
#define N_EDGES 400000
#define D 512
#define NCLS 40
#define SCAN_BLOCKS ((N_NODES + 255) / 256)
#define CSTRIDE 260   // C-tile LDS stride (elems): 520 B, 16B-aligned
#define SLOT 12288    // ring slot elems: A 4096 + B 8192

typedef __attribute__((ext_vector_type(8))) __bf16 bf16x8;
typedef __attribute__((ext_vector_type(4))) float f32x4;
typedef __attribute__((ext_vector_type(4))) float float4v;
typedef __attribute__((ext_vector_type(8))) unsigned short ushort8v;
typedef __attribute__((ext_vector_type(4))) unsigned short ushort4v;

#define AS1 __attribute__((address_space(1)))
#define AS3 __attribute__((address_space(3)))

__device__ __forceinline__ float bf2f(unsigned short u) {
  union { unsigned int i; float f; } v; v.i = ((unsigned int)u) << 16; return v.f;
}
__device__ __forceinline__ unsigned short f2bf(float f) {
  union { float f; unsigned int i; } v; v.f = f;
  unsigned int u = v.i;
  u += 0x7fffu + ((u >> 16) & 1u);  // round-nearest-even
  return (unsigned short)(u >> 16);
}

// ---------------- fused prep: zero counts + feat->bf16 + weights->bf16 -------
// Round-8: feat (102 MB f32) and weight-source reads are NON-TEMPORAL — they
// are single-use streams that were churning the 256 MB L3 every iteration and
// evicting hb (51 MB) between agg dispatches (agg FETCH stuck at 212 MB).
// nt keeps L3 capacity for the gather working set.
__global__ __launch_bounds__(256) void prep_kernel(
    const float* __restrict__ feat, const float* __restrict__ W0,
    const float* __restrict__ W1, const float* __restrict__ W2,
    const float* __restrict__ Wc, unsigned short* __restrict__ hb,
    unsigned short* __restrict__ Wt, unsigned short* __restrict__ Wct,
    int* __restrict__ counts) {
  const int T = gridDim.x * blockDim.x;
  const int gtid = blockIdx.x * blockDim.x + threadIdx.x;
  for (int i = gtid; i < N_NODES; i += T) counts[i] = 0;
  for (size_t c = gtid; c < (size_t)N_NODES * D / 4; c += (size_t)T) {
    size_t i = c * 4;
    float4v v = __builtin_nontemporal_load((const float4v*)&feat[i]);
    ushort4v o;
    o[0] = f2bf(v[0]); o[1] = f2bf(v[1]); o[2] = f2bf(v[2]); o[3] = f2bf(v[3]);
    *(ushort4v*)&hb[i] = o;
  }
  for (int i = gtid; i < 3 * D * D + 48 * D; i += T) {
    if (i < 3 * D * D) {
      int l = i >> 18;
      int r = i & (D * D - 1);
      int n = r >> 9, k = r & 511;
      const float* W = (l == 0) ? W0 : ((l == 1) ? W1 : W2);
      Wt[i] = f2bf(__builtin_nontemporal_load(&W[k * D + n]));
    } else {
      int r = i - 3 * D * D;
      int n = r >> 9, k = r & 511;
      Wct[r] = (n < NCLS) ? f2bf(__builtin_nontemporal_load(&Wc[k * NCLS + n]))
                          : (unsigned short)0;
    }
  }
}

// ---------------- CSR build ----------------
__global__ void hist_kernel(const int* __restrict__ dst, int* __restrict__ counts) {
  int e = blockIdx.x * blockDim.x + threadIdx.x;
  if (e < N_EDGES) atomicAdd(&counts[dst[e]], 1);
}

__global__ __launch_bounds__(256) void scan_local_kernel(const int* __restrict__ counts,
    int* __restrict__ incl, int* __restrict__ bsum) {
  __shared__ int s[256];
  int i = blockIdx.x * 256 + threadIdx.x;
  int v = (i < N_NODES) ? counts[i] : 0;
  s[threadIdx.x] = v;
  __syncthreads();
#pragma unroll
  for (int o = 1; o < 256; o <<= 1) {
    int t = (threadIdx.x >= o) ? s[threadIdx.x - o] : 0;
    __syncthreads();
    s[threadIdx.x] += t;
    __syncthreads();
  }
  if (i < N_NODES) incl[i] = s[threadIdx.x];
  if (threadIdx.x == 255) bsum[blockIdx.x] = s[255];
}

__global__ __launch_bounds__(256) void scan_bsum_kernel(int* __restrict__ bsum) {
  __shared__ int s[256];
  int v = (threadIdx.x < SCAN_BLOCKS) ? bsum[threadIdx.x] : 0;
  s[threadIdx.x] = v;
  __syncthreads();
#pragma unroll
  for (int o = 1; o < 256; o <<= 1) {
    int t = (threadIdx.x >= o) ? s[threadIdx.x - o] : 0;
    __syncthreads();
    s[threadIdx.x] += t;
    __syncthreads();
  }
  if (threadIdx.x < SCAN_BLOCKS) bsum[threadIdx.x] = s[threadIdx.x] - v;  // exclusive
}

__global__ __launch_bounds__(256) void scan_finish_kernel(const int* __restrict__ counts,
    const int* __restrict__ bsum, int* __restrict__ row_ptr, int* __restrict__ cursor) {
  int i = blockIdx.x * 256 + threadIdx.x;
  if (i < N_NODES) {
    int inc = cursor[i] + bsum[blockIdx.x];
    row_ptr[i + 1] = inc;
    cursor[i] = inc - counts[i];
    if (i == 0) row_ptr[0] = 0;
  }
}

__global__ void fill_kernel(const int* __restrict__ src, const int* __restrict__ dst,
                            int* __restrict__ cursor, int* __restrict__ esrc) {
  int e = blockIdx.x * blockDim.x + threadIdx.x;
  if (e < N_EDGES) {
    int pos = atomicAdd(&cursor[dst[e]], 1);
    esrc[pos] = src[e];
  }
}

// ---------------- aggregation: z = h + sum_{e: dst=i} h[src[e]] ----------------
// One wave per node (max TLP). Previously at ~3.7 TB/s with FETCH=212 MB;
// round-8 frees L3 (nt on prep/cls streams) so hb should become L3-resident.
__global__ __launch_bounds__(256) void agg_kernel(const unsigned short* __restrict__ hb,
    const int* __restrict__ row_ptr, const int* __restrict__ esrc,
    unsigned short* __restrict__ zb) {
  int w = threadIdx.x >> 6, lane = threadIdx.x & 63;
  int node = blockIdx.x * 4 + w;
  int col = lane * 8;
  const unsigned short* hcol = hb + col;
  float acc[8];
  ushort8v v = *(const ushort8v*)&hcol[(size_t)node * D];
#pragma unroll
  for (int t = 0; t < 8; ++t) acc[t] = bf2f(v[t]);
  int s = row_ptr[node], e = row_ptr[node + 1];
  int j = s;
  for (; j + 4 <= e; j += 4) {
    int i0 = esrc[j + 0], i1 = esrc[j + 1], i2 = esrc[j + 2], i3 = esrc[j + 3];
    ushort8v v0 = *(const ushort8v*)&hcol[(size_t)i0 * D];
    ushort8v v1 = *(const ushort8v*)&hcol[(size_t)i1 * D];
    ushort8v v2 = *(const ushort8v*)&hcol[(size_t)i2 * D];
    ushort8v v3 = *(const ushort8v*)&hcol[(size_t)i3 * D];
#pragma unroll
    for (int t = 0; t < 8; ++t) acc[t] += bf2f(v0[t]);
#pragma unroll
    for (int t = 0; t < 8; ++t) acc[t] += bf2f(v1[t]);
#pragma unroll
    for (int t = 0; t < 8; ++t) acc[t] += bf2f(v2[t]);
#pragma unroll
    for (int t = 0; t < 8; ++t) acc[t] += bf2f(v3[t]);
  }
  for (; j < e; ++j) {
    int sn = esrc[j];
    ushort8v nv = *(const ushort8v*)&hcol[(size_t)sn * D];
#pragma unroll
    for (int t = 0; t < 8; ++t) acc[t] += bf2f(nv[t]);
  }
  ushort8v o;
#pragma unroll
  for (int t = 0; t < 8; ++t) o[t] = f2bf(acc[t]);
  *(ushort8v*)&zb[(size_t)node * D + col] = o;
}

// ---------------- GEMM: Hout = relu(Z @ W + b), bf16 MFMA ----------------
// BM=128 x BN=256, BK=32, 512 threads = 8 waves (2m x 4n of 64x64).
// Round-5 proven structure (unchanged): minimum-line staging (A AND B via
// global_load_lds, 48 lines/wave/ktile), 3-slot LDS ring, 2-deep prefetch,
// rolled k-loop with rotating slot pointers, one raw s_barrier/iter,
// counted vmcnt(3), vmcnt(0) only at kt=15. Measured ~43 us = per-CU
// line-rate cap (393 KB/block x 3.05 blocks/CU / ~11.4 B/cyc/CU).
// XCD-chunked bijective swizzle (FETCH 29 MB). LDS 72 KB -> 2 blocks/CU.
__global__ __launch_bounds__(512, 4) void gemm_kernel(
    const unsigned short* __restrict__ Z, const unsigned short* __restrict__ Wt,
    const float* __restrict__ bias, unsigned short* __restrict__ Hout, int M) {
  __shared__ unsigned short smem[3 * SLOT];  // 72 KB: ring | Cs union (33280 elems)
  const int tid = threadIdx.x;
  const int lane = tid & 63;
  const int w = tid >> 6;               // 0..7
  const int wm = (w >> 2) * 64;         // {0,64}
  const int wn = (w & 3) * 64;          // {0,64,128,192}
  const int quad = lane >> 4;
  const int r16 = lane & 15;

  // bijective XCD-chunked swizzle over the linear block id
  const int nwg = gridDim.x * gridDim.y;
  const int lin = blockIdx.y * gridDim.x + blockIdx.x;
  const int q = nwg >> 3, r = nwg & 7;
  const int xcd = lin & 7, idx = lin >> 3;
  const int wg = (xcd < r ? xcd * (q + 1) : r * (q + 1) + (xcd - r) * q) + idx;
  const int n0 = (wg & 1) * 256;
  const int m0 = (wg >> 1) * 128;

  f32x4 acc[4][4];
#pragma unroll
  for (int i = 0; i < 4; ++i)
#pragma unroll
    for (int j = 0; j < 4; ++j)
      acc[i][j] = (f32x4){0.f, 0.f, 0.f, 0.f};

  const int srow = lane >> 2;        // staging row within 16-row chunk
  const int skk = (lane & 3) * 8;    // staging k offset (elems)
  int gm_st = m0 + w * 16 + srow; if (gm_st > M - 1) gm_st = M - 1;  // clamp; masked at store
  const unsigned short* Zst = Z + (size_t)gm_st * D + skk;
  const unsigned short* Bst0 = Wt + (size_t)(n0 + w * 32 + srow) * D + skk;
  const unsigned short* Bst1 = Wt + (size_t)(n0 + w * 32 + 16 + srow) * D + skk;

  // stage group for k-tile kt into ring slot p: 3 global_load_lds (A,B,B)
  auto stage = [&](int kt_, unsigned short* p) {
    __builtin_amdgcn_global_load_lds((AS1 void*)(void*)(Zst + kt_ * 32),
                                     (AS3 void*)(p + w * 512), 16, 0, 0);
    __builtin_amdgcn_global_load_lds((AS1 void*)(void*)(Bst0 + kt_ * 32),
                                     (AS3 void*)(p + 4096 + (w * 2 + 0) * 512), 16, 0, 0);
    __builtin_amdgcn_global_load_lds((AS1 void*)(void*)(Bst1 + kt_ * 32),
                                     (AS3 void*)(p + 4096 + (w * 2 + 1) * 512), 16, 0, 0);
  };

  unsigned short* p0 = smem;             // compute slot (k-tile kt)
  unsigned short* p1 = smem + SLOT;      // in-flight slot (kt+1)
  unsigned short* p2 = smem + 2 * SLOT;  // stage target (kt+2)

  // ---- prologue: groups 0 and 1 in flight
  stage(0, p0);
  stage(1, p1);

  for (int kt = 0; kt < 16; ++kt) {
    // retire group kt (in-order); group kt+1's 3 loads stay in flight
    if (kt < 15) asm volatile("s_waitcnt vmcnt(3)" ::: "memory");
    else         asm volatile("s_waitcnt vmcnt(0)" ::: "memory");
    __builtin_amdgcn_s_barrier();   // all waves' group-kt slices staged
    __builtin_amdgcn_sched_barrier(0);  // stage below must not hoist above barrier
    if (kt + 2 < 16) stage(kt + 2, p2); // p2's prior readers finished pre-barrier
    __builtin_amdgcn_sched_barrier(0);
    const unsigned short* Ac = p0;
    const unsigned short* Bc = p0 + 4096;
    bf16x8 a[4];
#pragma unroll
    for (int i = 0; i < 4; ++i)
      a[i] = *(const bf16x8*)&Ac[(wm + i * 16 + r16) * 32 + quad * 8];
#pragma unroll
    for (int j = 0; j < 4; ++j) {
      bf16x8 b = *(const bf16x8*)&Bc[(wn + j * 16 + r16) * 32 + quad * 8];
#pragma unroll
      for (int i = 0; i < 4; ++i)
        acc[i][j] = __builtin_amdgcn_mfma_f32_16x16x32_bf16(a[i], b, acc[i][j], 0, 0, 0);
    }
    unsigned short* t = p0; p0 = p1; p1 = p2; p2 = t;  // rotate ring
  }

  // ---- epilogue: bias+relu -> Cs (128 x 256, stride 260) -> coalesced stores
  __syncthreads();  // all frag reads done before overwriting smem (vmcnt already 0)
  unsigned short* Cs = smem;
#pragma unroll
  for (int j = 0; j < 4; ++j) {
    float bv = bias[n0 + wn + j * 16 + r16];
#pragma unroll
    for (int i = 0; i < 4; ++i) {
      int crow = wm + i * 16 + quad * 4;
      int ccol = wn + j * 16 + r16;
#pragma unroll
      for (int rr = 0; rr < 4; ++rr) {
        float vv = acc[i][j][rr] + bv;
        vv = vv > 0.f ? vv : 0.f;
        Cs[(crow + rr) * CSTRIDE + ccol] = f2bf(vv);
      }
    }
  }
  __syncthreads();
  // copy-out: per instr 512 threads x 16B: 32 lanes cover one 512B row-half; rows
  // it*16 + tid/32 cover 0..127 over 8 iters. Full 64B lines -> no write amp.
#pragma unroll
  for (int it = 0; it < 8; ++it) {
    int row = it * 16 + (tid >> 5);
    int colofs = (tid & 31) * 8;
    int gm = m0 + row;
    if (gm < M) {
      ushort8v vv = *(const ushort8v*)&Cs[row * CSTRIDE + colofs];
      *(ushort8v*)&Hout[(size_t)gm * D + n0 + colofs] = vv;
    }
  }
}

// ---------------- classifier: out = h3 @ Wc + bc  (bf16 MFMA, no LDS) ----------------
// Round-8: f32 output stores are non-temporal (8 MB single-use stream).
__global__ __launch_bounds__(256) void cls_kernel(const unsigned short* __restrict__ hb,
    const unsigned short* __restrict__ Wct, const float* __restrict__ bc,
    float* __restrict__ out) {
  int w = threadIdx.x >> 6, lane = threadIdx.x & 63;
  int quad = lane >> 4, r16 = lane & 15;
  int nb = blockIdx.x * 64 + w * 16;
  int arow = nb + r16; if (arow > N_NODES - 1) arow = N_NODES - 1;
  f32x4 acc[3];
#pragma unroll
  for (int j = 0; j < 3; ++j) acc[j] = (f32x4){0.f, 0.f, 0.f, 0.f};
#pragma unroll 4
  for (int kt = 0; kt < 16; ++kt) {
    int kk = kt * 32 + quad * 8;
    bf16x8 a = *(const bf16x8*)&hb[(size_t)arow * D + kk];
#pragma unroll
    for (int j = 0; j < 3; ++j) {
      bf16x8 b = *(const bf16x8*)&Wct[(size_t)(j * 16 + r16) * D + kk];
      acc[j] = __builtin_amdgcn_mfma_f32_16x16x32_bf16(a, b, acc[j], 0, 0, 0);
    }
  }
#pragma unroll
  for (int j = 0; j < 3; ++j) {
    int gn = j * 16 + r16;
    if (gn < NCLS) {
      float bv = bc[gn];
#pragma unroll
      for (int r = 0; r < 4; ++r) {
        int gm = nb + quad * 4 + r;
        if (gm < N_NODES)
          __builtin_nontemporal_store(acc[j][r] + bv, &out[(size_t)gm * NCLS + gn]);
      }
    }
  }
}

extern "C" void kernel_launch(void* const* d_in, const int* in_sizes, int n_in,
                              void* d_out, int out_size, void* d_ws, size_t ws_size,
                              hipStream_t stream) {
  const float* feat = (const float*)d_in[0];
  const int* src = (const int*)d_in[1];
  const int* dst = (const int*)d_in[2];
  const float* W0 = (const float*)d_in[3];
  const float* b0 = (const float*)d_in[4];
  const float* W1 = (const float*)d_in[5];
  const float* b1 = (const float*)d_in[6];
  const float* W2 = (const float*)d_in[7];
  const float* b2 = (const float*)d_in[8];
  const float* Wc = (const float*)d_in[9];
  const float* bc = (const float*)d_in[10];
  float* out = (float*)d_out;

  char* ws = (char*)d_ws;
  size_t off = 0;
  auto alloc = [&](size_t bytes) {
    char* p = ws + off;
    off += (bytes + 255) & ~(size_t)255;
    return p;
  };
  unsigned short* hb = (unsigned short*)alloc((size_t)N_NODES * D * 2);   // 51.2 MB
  unsigned short* zb = (unsigned short*)alloc((size_t)N_NODES * D * 2);   // 51.2 MB
  unsigned short* Wt = (unsigned short*)alloc((size_t)3 * D * D * 2);     // 1.5 MB
  unsigned short* Wct = (unsigned short*)alloc((size_t)48 * D * 2);       // 49 KB
  int* row_ptr = (int*)alloc((size_t)(N_NODES + 1) * 4);
  int* counts  = (int*)alloc((size_t)N_NODES * 4);
  int* cursor  = (int*)alloc((size_t)N_NODES * 4);
  int* esrc    = (int*)alloc((size_t)N_EDGES * 4);
  int* bsum    = (int*)alloc((size_t)256 * 4);

  // fused prep (zero counts + cvt feat + cvt weights), then CSR build
  prep_kernel<<<2048, 256, 0, stream>>>(feat, W0, W1, W2, Wc, hb, Wt, Wct, counts);
  hist_kernel<<<(N_EDGES + 255) / 256, 256, 0, stream>>>(dst, counts);
  scan_local_kernel<<<SCAN_BLOCKS, 256, 0, stream>>>(counts, cursor, bsum);
  scan_bsum_kernel<<<1, 256, 0, stream>>>(bsum);
  scan_finish_kernel<<<SCAN_BLOCKS, 256, 0, stream>>>(counts, bsum, row_ptr, cursor);
  fill_kernel<<<(N_EDGES + 255) / 256, 256, 0, stream>>>(src, dst, cursor, esrc);

  dim3 ggrid(2, (N_NODES + 127) / 128);  // remapped in-kernel via XCD-chunked swizzle
  const float* bs[3] = {b0, b1, b2};
  for (int l = 0; l < 3; ++l) {
    agg_kernel<<<N_NODES / 4, 256, 0, stream>>>(hb, row_ptr, esrc, zb);
    gemm_kernel<<<ggrid, 512, 0, stream>>>(zb, Wt + (size_t)l * D * D, bs[l], hb, N_NODES);
  }
  cls_kernel<<<(N_NODES + 63) / 64, 256, 0, stream>>>(hb, Wct, bc, out);
}

// Round 9
// 568.199 us; speedup vs baseline: 1.0153x; 1.0153x over previous
//
#include <hip/hip_runtime.h>

#define N_NODES 50000
#define N_EDGES 400000
#define D 512
#define NCLS 40
#define SCAN_BLOCKS ((N_NODES + 255) / 256)
#define CSTRIDE 260   // C-tile LDS stride (elems): 520 B, 16B-aligned
#define SLOT 16384    // ring slot elems: A 8192 (256x32) + B 8192 (256x32)

typedef __attribute__((ext_vector_type(8))) __bf16 bf16x8;
typedef __attribute__((ext_vector_type(4))) float f32x4;
typedef __attribute__((ext_vector_type(4))) float float4v;
typedef __attribute__((ext_vector_type(8))) unsigned short ushort8v;
typedef __attribute__((ext_vector_type(4))) unsigned short ushort4v;

#define AS1 __attribute__((address_space(1)))
#define AS3 __attribute__((address_space(3)))

__device__ __forceinline__ float bf2f(unsigned short u) {
  union { unsigned int i; float f; } v; v.i = ((unsigned int)u) << 16; return v.f;
}
__device__ __forceinline__ unsigned short f2bf(float f) {
  union { float f; unsigned int i; } v; v.f = f;
  unsigned int u = v.i;
  u += 0x7fffu + ((u >> 16) & 1u);  // round-nearest-even
  return (unsigned short)(u >> 16);
}

// ---------------- fused prep: zero counts + feat->bf16 + weights->bf16 -------
__global__ __launch_bounds__(256) void prep_kernel(
    const float* __restrict__ feat, const float* __restrict__ W0,
    const float* __restrict__ W1, const float* __restrict__ W2,
    const float* __restrict__ Wc, unsigned short* __restrict__ hb,
    unsigned short* __restrict__ Wt, unsigned short* __restrict__ Wct,
    int* __restrict__ counts) {
  const int T = gridDim.x * blockDim.x;
  const int gtid = blockIdx.x * blockDim.x + threadIdx.x;
  for (int i = gtid; i < N_NODES; i += T) counts[i] = 0;
  for (size_t c = gtid; c < (size_t)N_NODES * D / 4; c += (size_t)T) {
    size_t i = c * 4;
    float4v v = __builtin_nontemporal_load((const float4v*)&feat[i]);
    ushort4v o;
    o[0] = f2bf(v[0]); o[1] = f2bf(v[1]); o[2] = f2bf(v[2]); o[3] = f2bf(v[3]);
    *(ushort4v*)&hb[i] = o;
  }
  for (int i = gtid; i < 3 * D * D + 48 * D; i += T) {
    if (i < 3 * D * D) {
      int l = i >> 18;
      int r = i & (D * D - 1);
      int n = r >> 9, k = r & 511;
      const float* W = (l == 0) ? W0 : ((l == 1) ? W1 : W2);
      Wt[i] = f2bf(__builtin_nontemporal_load(&W[k * D + n]));
    } else {
      int r = i - 3 * D * D;
      int n = r >> 9, k = r & 511;
      Wct[r] = (n < NCLS) ? f2bf(__builtin_nontemporal_load(&Wc[k * NCLS + n]))
                          : (unsigned short)0;
    }
  }
}

// ---------------- CSR build ----------------
__global__ void hist_kernel(const int* __restrict__ dst, int* __restrict__ counts) {
  int e = blockIdx.x * blockDim.x + threadIdx.x;
  if (e < N_EDGES) atomicAdd(&counts[dst[e]], 1);
}

__global__ __launch_bounds__(256) void scan_local_kernel(const int* __restrict__ counts,
    int* __restrict__ incl, int* __restrict__ bsum) {
  __shared__ int s[256];
  int i = blockIdx.x * 256 + threadIdx.x;
  int v = (i < N_NODES) ? counts[i] : 0;
  s[threadIdx.x] = v;
  __syncthreads();
#pragma unroll
  for (int o = 1; o < 256; o <<= 1) {
    int t = (threadIdx.x >= o) ? s[threadIdx.x - o] : 0;
    __syncthreads();
    s[threadIdx.x] += t;
    __syncthreads();
  }
  if (i < N_NODES) incl[i] = s[threadIdx.x];
  if (threadIdx.x == 255) bsum[blockIdx.x] = s[255];
}

__global__ __launch_bounds__(256) void scan_bsum_kernel(int* __restrict__ bsum) {
  __shared__ int s[256];
  int v = (threadIdx.x < SCAN_BLOCKS) ? bsum[threadIdx.x] : 0;
  s[threadIdx.x] = v;
  __syncthreads();
#pragma unroll
  for (int o = 1; o < 256; o <<= 1) {
    int t = (threadIdx.x >= o) ? s[threadIdx.x - o] : 0;
    __syncthreads();
    s[threadIdx.x] += t;
    __syncthreads();
  }
  if (threadIdx.x < SCAN_BLOCKS) bsum[threadIdx.x] = s[threadIdx.x] - v;  // exclusive
}

__global__ __launch_bounds__(256) void scan_finish_kernel(const int* __restrict__ counts,
    const int* __restrict__ bsum, int* __restrict__ row_ptr, int* __restrict__ cursor) {
  int i = blockIdx.x * 256 + threadIdx.x;
  if (i < N_NODES) {
    int inc = cursor[i] + bsum[blockIdx.x];
    row_ptr[i + 1] = inc;
    cursor[i] = inc - counts[i];
    if (i == 0) row_ptr[0] = 0;
  }
}

__global__ void fill_kernel(const int* __restrict__ src, const int* __restrict__ dst,
                            int* __restrict__ cursor, int* __restrict__ esrc) {
  int e = blockIdx.x * blockDim.x + threadIdx.x;
  if (e < N_EDGES) {
    int pos = atomicAdd(&cursor[dst[e]], 1);
    esrc[pos] = src[e];
  }
}

// ---------------- aggregation: z = h + sum_{e: dst=i} h[src[e]] ----------------
// One wave per node. MSHR/latency-capped on random line fills (~4.9 B/cyc/CU
// fabric; structure-insensitive across rounds 0-8). At its ceiling — accept.
__global__ __launch_bounds__(256) void agg_kernel(const unsigned short* __restrict__ hb,
    const int* __restrict__ row_ptr, const int* __restrict__ esrc,
    unsigned short* __restrict__ zb) {
  int w = threadIdx.x >> 6, lane = threadIdx.x & 63;
  int node = blockIdx.x * 4 + w;
  int col = lane * 8;
  const unsigned short* hcol = hb + col;
  float acc[8];
  ushort8v v = *(const ushort8v*)&hcol[(size_t)node * D];
#pragma unroll
  for (int t = 0; t < 8; ++t) acc[t] = bf2f(v[t]);
  int s = row_ptr[node], e = row_ptr[node + 1];
  int j = s;
  for (; j + 4 <= e; j += 4) {
    int i0 = esrc[j + 0], i1 = esrc[j + 1], i2 = esrc[j + 2], i3 = esrc[j + 3];
    ushort8v v0 = *(const ushort8v*)&hcol[(size_t)i0 * D];
    ushort8v v1 = *(const ushort8v*)&hcol[(size_t)i1 * D];
    ushort8v v2 = *(const ushort8v*)&hcol[(size_t)i2 * D];
    ushort8v v3 = *(const ushort8v*)&hcol[(size_t)i3 * D];
#pragma unroll
    for (int t = 0; t < 8; ++t) acc[t] += bf2f(v0[t]);
#pragma unroll
    for (int t = 0; t < 8; ++t) acc[t] += bf2f(v1[t]);
#pragma unroll
    for (int t = 0; t < 8; ++t) acc[t] += bf2f(v2[t]);
#pragma unroll
    for (int t = 0; t < 8; ++t) acc[t] += bf2f(v3[t]);
  }
  for (; j < e; ++j) {
    int sn = esrc[j];
    ushort8v nv = *(const ushort8v*)&hcol[(size_t)sn * D];
#pragma unroll
    for (int t = 0; t < 8; ++t) acc[t] += bf2f(nv[t]);
  }
  ushort8v o;
#pragma unroll
  for (int t = 0; t < 8; ++t) o[t] = f2bf(acc[t]);
  *(ushort8v*)&zb[(size_t)node * D + col] = o;
}

// ---------------- GEMM: Hout = relu(Z @ W + b), bf16 MFMA ----------------
// Round-9: BM=256 x BN=256, BK=32, ONE 1024-thread block (16 waves, 4m x 4n
// of 64x64). Staged bytes/layer: 51.2*(512/BN) + 0.5*(M/BM) = 200 MB vs
// 297 MB at 128x256 — B-staging halves because BM doubles. Per-CU wave
// count unchanged (16), so the staging line-issue concurrency (the measured
// cap) is preserved; line touches/CU drop ~12% after the 392-block 2-round
// imbalance. Same r5-proven pipeline: 3-slot LDS ring (96 KB, 1 block/CU),
// 2-deep prefetch, rolled loop with rotating slot pointers, one raw
// s_barrier/iter, counted vmcnt(2) (groups are now 2 loads: A,B), vmcnt(0)
// only at kt=15. Epilogue in 2 half-passes (Cs 128x260 = 66.6 KB fits ring).
// 392 = 8*49: XCD swizzle exactly balanced.
__global__ __launch_bounds__(1024, 4) void gemm_kernel(
    const unsigned short* __restrict__ Z, const unsigned short* __restrict__ Wt,
    const float* __restrict__ bias, unsigned short* __restrict__ Hout, int M) {
  __shared__ unsigned short smem[3 * SLOT];  // 96 KB: ring | Cs union (49152 elems)
  const int tid = threadIdx.x;
  const int lane = tid & 63;
  const int w = tid >> 6;               // 0..15
  const int wm = (w >> 2) * 64;         // {0,64,128,192}
  const int wn = (w & 3) * 64;          // {0,64,128,192}
  const int quad = lane >> 4;
  const int r16 = lane & 15;

  // bijective XCD-chunked swizzle over the linear block id
  const int nwg = gridDim.x * gridDim.y;
  const int lin = blockIdx.y * gridDim.x + blockIdx.x;
  const int q = nwg >> 3, r = nwg & 7;
  const int xcd = lin & 7, idx = lin >> 3;
  const int wg = (xcd < r ? xcd * (q + 1) : r * (q + 1) + (xcd - r) * q) + idx;
  const int n0 = (wg & 1) * 256;
  const int m0 = (wg >> 1) * 256;

  f32x4 acc[4][4];
#pragma unroll
  for (int i = 0; i < 4; ++i)
#pragma unroll
    for (int j = 0; j < 4; ++j)
      acc[i][j] = (f32x4){0.f, 0.f, 0.f, 0.f};

  const int srow = lane >> 2;        // staging row within 16-row chunk
  const int skk = (lane & 3) * 8;    // staging k offset (elems)
  int gm_st = m0 + w * 16 + srow; if (gm_st > M - 1) gm_st = M - 1;  // clamp; masked at store
  const unsigned short* Zst = Z + (size_t)gm_st * D + skk;
  const unsigned short* Bst = Wt + (size_t)(n0 + w * 16 + srow) * D + skk;

  // stage group for k-tile kt into ring slot p: 2 global_load_lds (A,B)
  auto stage = [&](int kt_, unsigned short* p) {
    __builtin_amdgcn_global_load_lds((AS1 void*)(void*)(Zst + kt_ * 32),
                                     (AS3 void*)(p + w * 512), 16, 0, 0);
    __builtin_amdgcn_global_load_lds((AS1 void*)(void*)(Bst + kt_ * 32),
                                     (AS3 void*)(p + 8192 + w * 512), 16, 0, 0);
  };

  unsigned short* p0 = smem;             // compute slot (k-tile kt)
  unsigned short* p1 = smem + SLOT;      // in-flight slot (kt+1)
  unsigned short* p2 = smem + 2 * SLOT;  // stage target (kt+2)

  // ---- prologue: groups 0 and 1 in flight (4 loads)
  stage(0, p0);
  stage(1, p1);

  for (int kt = 0; kt < 16; ++kt) {
    // retire group kt (in-order); group kt+1's 2 loads stay in flight
    if (kt < 15) asm volatile("s_waitcnt vmcnt(2)" ::: "memory");
    else         asm volatile("s_waitcnt vmcnt(0)" ::: "memory");
    __builtin_amdgcn_s_barrier();   // all waves' group-kt slices staged
    __builtin_amdgcn_sched_barrier(0);  // stage below must not hoist above barrier
    if (kt + 2 < 16) stage(kt + 2, p2); // p2's prior readers finished pre-barrier
    __builtin_amdgcn_sched_barrier(0);
    const unsigned short* Ac = p0;
    const unsigned short* Bc = p0 + 8192;
    bf16x8 a[4];
#pragma unroll
    for (int i = 0; i < 4; ++i)
      a[i] = *(const bf16x8*)&Ac[(wm + i * 16 + r16) * 32 + quad * 8];
#pragma unroll
    for (int j = 0; j < 4; ++j) {
      bf16x8 b = *(const bf16x8*)&Bc[(wn + j * 16 + r16) * 32 + quad * 8];
#pragma unroll
      for (int i = 0; i < 4; ++i)
        acc[i][j] = __builtin_amdgcn_mfma_f32_16x16x32_bf16(a[i], b, acc[i][j], 0, 0, 0);
    }
    unsigned short* t = p0; p0 = p1; p1 = p2; p2 = t;  // rotate ring
  }

  // ---- epilogue: 2 half-passes of 128 rows: bias+relu -> Cs -> coalesced stores
  unsigned short* Cs = smem;
  float bv[4];
#pragma unroll
  for (int j = 0; j < 4; ++j) bv[j] = bias[n0 + wn + j * 16 + r16];
#pragma unroll
  for (int pass = 0; pass < 2; ++pass) {
    __syncthreads();  // pass 0: frag reads done; pass 1: prior copy-out done
    if ((w >> 3) == pass) {  // waves with wm in this 128-row half
#pragma unroll
      for (int j = 0; j < 4; ++j) {
#pragma unroll
        for (int i = 0; i < 4; ++i) {
          int crow = (wm & 127) + i * 16 + quad * 4;
          int ccol = wn + j * 16 + r16;
#pragma unroll
          for (int rr = 0; rr < 4; ++rr) {
            float vv = acc[i][j][rr] + bv[j];
            vv = vv > 0.f ? vv : 0.f;
            Cs[(crow + rr) * CSTRIDE + ccol] = f2bf(vv);
          }
        }
      }
    }
    __syncthreads();
    // copy-out: 1024 thr x 16B; 32 lanes cover one 512B row; 32 rows/iter, 4 iters
#pragma unroll
    for (int it = 0; it < 4; ++it) {
      int row = it * 32 + (tid >> 5);
      int colofs = (tid & 31) * 8;
      int gm = m0 + pass * 128 + row;
      if (gm < M) {
        ushort8v vv = *(const ushort8v*)&Cs[row * CSTRIDE + colofs];
        *(ushort8v*)&Hout[(size_t)gm * D + n0 + colofs] = vv;
      }
    }
  }
}

// ---------------- classifier: out = h3 @ Wc + bc  (bf16 MFMA, no LDS) ----------------
__global__ __launch_bounds__(256) void cls_kernel(const unsigned short* __restrict__ hb,
    const unsigned short* __restrict__ Wct, const float* __restrict__ bc,
    float* __restrict__ out) {
  int w = threadIdx.x >> 6, lane = threadIdx.x & 63;
  int quad = lane >> 4, r16 = lane & 15;
  int nb = blockIdx.x * 64 + w * 16;
  int arow = nb + r16; if (arow > N_NODES - 1) arow = N_NODES - 1;
  f32x4 acc[3];
#pragma unroll
  for (int j = 0; j < 3; ++j) acc[j] = (f32x4){0.f, 0.f, 0.f, 0.f};
#pragma unroll 4
  for (int kt = 0; kt < 16; ++kt) {
    int kk = kt * 32 + quad * 8;
    bf16x8 a = *(const bf16x8*)&hb[(size_t)arow * D + kk];
#pragma unroll
    for (int j = 0; j < 3; ++j) {
      bf16x8 b = *(const bf16x8*)&Wct[(size_t)(j * 16 + r16) * D + kk];
      acc[j] = __builtin_amdgcn_mfma_f32_16x16x32_bf16(a, b, acc[j], 0, 0, 0);
    }
  }
#pragma unroll
  for (int j = 0; j < 3; ++j) {
    int gn = j * 16 + r16;
    if (gn < NCLS) {
      float bv = bc[gn];
#pragma unroll
      for (int r = 0; r < 4; ++r) {
        int gm = nb + quad * 4 + r;
        if (gm < N_NODES)
          __builtin_nontemporal_store(acc[j][r] + bv, &out[(size_t)gm * NCLS + gn]);
      }
    }
  }
}

extern "C" void kernel_launch(void* const* d_in, const int* in_sizes, int n_in,
                              void* d_out, int out_size, void* d_ws, size_t ws_size,
                              hipStream_t stream) {
  const float* feat = (const float*)d_in[0];
  const int* src = (const int*)d_in[1];
  const int* dst = (const int*)d_in[2];
  const float* W0 = (const float*)d_in[3];
  const float* b0 = (const float*)d_in[4];
  const float* W1 = (const float*)d_in[5];
  const float* b1 = (const float*)d_in[6];
  const float* W2 = (const float*)d_in[7];
  const float* b2 = (const float*)d_in[8];
  const float* Wc = (const float*)d_in[9];
  const float* bc = (const float*)d_in[10];
  float* out = (float*)d_out;

  char* ws = (char*)d_ws;
  size_t off = 0;
  auto alloc = [&](size_t bytes) {
    char* p = ws + off;
    off += (bytes + 255) & ~(size_t)255;
    return p;
  };
  unsigned short* hb = (unsigned short*)alloc((size_t)N_NODES * D * 2);   // 51.2 MB
  unsigned short* zb = (unsigned short*)alloc((size_t)N_NODES * D * 2);   // 51.2 MB
  unsigned short* Wt = (unsigned short*)alloc((size_t)3 * D * D * 2);     // 1.5 MB
  unsigned short* Wct = (unsigned short*)alloc((size_t)48 * D * 2);       // 49 KB
  int* row_ptr = (int*)alloc((size_t)(N_NODES + 1) * 4);
  int* counts  = (int*)alloc((size_t)N_NODES * 4);
  int* cursor  = (int*)alloc((size_t)N_NODES * 4);
  int* esrc    = (int*)alloc((size_t)N_EDGES * 4);
  int* bsum    = (int*)alloc((size_t)256 * 4);

  // fused prep (zero counts + cvt feat + cvt weights), then CSR build
  prep_kernel<<<2048, 256, 0, stream>>>(feat, W0, W1, W2, Wc, hb, Wt, Wct, counts);
  hist_kernel<<<(N_EDGES + 255) / 256, 256, 0, stream>>>(dst, counts);
  scan_local_kernel<<<SCAN_BLOCKS, 256, 0, stream>>>(counts, cursor, bsum);
  scan_bsum_kernel<<<1, 256, 0, stream>>>(bsum);
  scan_finish_kernel<<<SCAN_BLOCKS, 256, 0, stream>>>(counts, bsum, row_ptr, cursor);
  fill_kernel<<<(N_EDGES + 255) / 256, 256, 0, stream>>>(src, dst, cursor, esrc);

  dim3 ggrid(2, (N_NODES + 255) / 256);  // 2 n-tiles x 196 m-tiles = 392 = 8*49
  const float* bs[3] = {b0, b1, b2};
  for (int l = 0; l < 3; ++l) {
    agg_kernel<<<N_NODES / 4, 256, 0, stream>>>(hb, row_ptr, esrc, zb);
    gemm_kernel<<<ggrid, 1024, 0, stream>>>(zb, Wt + (size_t)l * D * D, bs[l], hb, N_NODES);
  }
  cls_kernel<<<(N_NODES + 63) / 64, 256, 0, stream>>>(hb, Wct, bc, out);
}